// Round 1
// baseline (461.320 us; speedup 1.0000x reference)
//
#include <hip/hip_runtime.h>
#include <hip/hip_bf16.h>
#include <math.h>

// Problem constants
#define B_SZ 8
#define LSEQ 4096
#define NDIM 256
#define HDIM 256
#define MROWS (B_SZ * LSEQ)     // 32768
#define CH 32                   // chunk length for the scan
#define NC (LSEQ / CH)          // 128 chunks

// ---------------------------------------------------------------------------
// Kernel P: compute Lambda (re/im) and gamma from nu_log / theta_log
// ---------------------------------------------------------------------------
__global__ void k_params(const float* __restrict__ nu_log,
                         const float* __restrict__ th_log,
                         float* __restrict__ lamRe,
                         float* __restrict__ lamIm,
                         float* __restrict__ gam) {
    int n = threadIdx.x;  // 256 threads
    float nu  = expf(nu_log[n]);
    float th  = expf(th_log[n]);
    float mod = expf(-nu);
    lamRe[n] = mod * cosf(th);
    lamIm[n] = mod * sinf(th);
    gam[n]   = sqrtf(fmaxf(1.0f - mod * mod, 0.0f));
}

// ---------------------------------------------------------------------------
// Kernel G1: Bu = x @ B_norm^T   (two real planes, scaled by gamma[n])
// x: [M, H] row-major.  Bre/Bim: [N, H] row-major (dot over h).
// out planes buRe/buIm: [M, N].
// Tile 64(m) x 64(n), 256 threads, 4x4 per thread, K-tile 16.
// ---------------------------------------------------------------------------
__launch_bounds__(256)
__global__ void k_bu(const float* __restrict__ x,
                     const float* __restrict__ Bre,
                     const float* __restrict__ Bim,
                     const float* __restrict__ gam,
                     float* __restrict__ buRe,
                     float* __restrict__ buIm) {
    __shared__ float As[64][17];
    __shared__ float W1s[64][17];
    __shared__ float W2s[64][17];

    const int tid = threadIdx.x;
    const int tx = tid & 15;          // n direction
    const int ty = tid >> 4;          // m direction
    const int m0 = blockIdx.x * 64;
    const int n0 = blockIdx.y * 64;

    const int lr = tid >> 2;          // 0..63 : row within tile
    const int lc = (tid & 3) * 4;     // 0,4,8,12 : col within k-tile

    float acc1[4][4] = {};
    float acc2[4][4] = {};

    for (int k0 = 0; k0 < HDIM; k0 += 16) {
        float4 a4  = *(const float4*)(x   + (size_t)(m0 + lr) * HDIM + k0 + lc);
        float4 w14 = *(const float4*)(Bre + (size_t)(n0 + lr) * HDIM + k0 + lc);
        float4 w24 = *(const float4*)(Bim + (size_t)(n0 + lr) * HDIM + k0 + lc);
        __syncthreads();
        As[lr][lc + 0] = a4.x;  As[lr][lc + 1] = a4.y;
        As[lr][lc + 2] = a4.z;  As[lr][lc + 3] = a4.w;
        W1s[lr][lc + 0] = w14.x; W1s[lr][lc + 1] = w14.y;
        W1s[lr][lc + 2] = w14.z; W1s[lr][lc + 3] = w14.w;
        W2s[lr][lc + 0] = w24.x; W2s[lr][lc + 1] = w24.y;
        W2s[lr][lc + 2] = w24.z; W2s[lr][lc + 3] = w24.w;
        __syncthreads();
#pragma unroll
        for (int kk = 0; kk < 16; ++kk) {
            float a[4], w1[4], w2[4];
#pragma unroll
            for (int i = 0; i < 4; ++i) a[i]  = As[ty * 4 + i][kk];
#pragma unroll
            for (int j = 0; j < 4; ++j) w1[j] = W1s[tx * 4 + j][kk];
#pragma unroll
            for (int j = 0; j < 4; ++j) w2[j] = W2s[tx * 4 + j][kk];
#pragma unroll
            for (int i = 0; i < 4; ++i)
#pragma unroll
                for (int j = 0; j < 4; ++j) {
                    acc1[i][j] = fmaf(a[i], w1[j], acc1[i][j]);
                    acc2[i][j] = fmaf(a[i], w2[j], acc2[i][j]);
                }
        }
    }

    float g[4];
#pragma unroll
    for (int j = 0; j < 4; ++j) g[j] = gam[n0 + tx * 4 + j];

#pragma unroll
    for (int i = 0; i < 4; ++i) {
        int m = m0 + ty * 4 + i;
        float4 o1, o2;
        o1.x = acc1[i][0] * g[0]; o1.y = acc1[i][1] * g[1];
        o1.z = acc1[i][2] * g[2]; o1.w = acc1[i][3] * g[3];
        o2.x = acc2[i][0] * g[0]; o2.y = acc2[i][1] * g[1];
        o2.z = acc2[i][2] * g[2]; o2.w = acc2[i][3] * g[3];
        *(float4*)(buRe + (size_t)m * NDIM + n0 + tx * 4) = o1;
        *(float4*)(buIm + (size_t)m * NDIM + n0 + tx * 4) = o2;
    }
}

// ---------------------------------------------------------------------------
// Kernel S1: per-chunk local scan, s starts at 0; store chunk-final state.
// grid (NC, B_SZ), block 256 (one thread per n).
// ---------------------------------------------------------------------------
__launch_bounds__(256)
__global__ void k_scan1(const float* __restrict__ buRe,
                        const float* __restrict__ buIm,
                        const float* __restrict__ lamRe,
                        const float* __restrict__ lamIm,
                        float* __restrict__ finRe,
                        float* __restrict__ finIm) {
    const int c = blockIdx.x;
    const int b = blockIdx.y;
    const int n = threadIdx.x;
    const float lr = lamRe[n];
    const float li = lamIm[n];
    size_t base = ((size_t)b * LSEQ + (size_t)c * CH) * NDIM + n;
    float sr = 0.0f, si = 0.0f;
#pragma unroll 8
    for (int i = 0; i < CH; ++i) {
        float ur = buRe[base + (size_t)i * NDIM];
        float ui = buIm[base + (size_t)i * NDIM];
        float nr = fmaf(lr, sr, fmaf(-li, si, ur));
        float ni = fmaf(lr, si, fmaf(li, sr, ui));
        sr = nr; si = ni;
    }
    size_t fidx = ((size_t)b * NC + c) * NDIM + n;
    finRe[fidx] = sr;
    finIm[fidx] = si;
}

// ---------------------------------------------------------------------------
// Kernel C2: sequential prefix over chunk carries.
// carry[b][c] = state at end of chunk c-1 (carry[b][0] = 0).
// grid B_SZ blocks, 256 threads (one per n).
// ---------------------------------------------------------------------------
__launch_bounds__(256)
__global__ void k_carry(const float* __restrict__ lamRe,
                        const float* __restrict__ lamIm,
                        const float* __restrict__ finRe,
                        const float* __restrict__ finIm,
                        float* __restrict__ carRe,
                        float* __restrict__ carIm) {
    const int b = blockIdx.x;
    const int n = threadIdx.x;
    const float lr = lamRe[n];
    const float li = lamIm[n];
    // lamK = Lambda^CH
    float kr = 1.0f, ki = 0.0f;
#pragma unroll
    for (int i = 0; i < CH; ++i) {
        float t = kr * lr - ki * li;
        ki = fmaf(kr, li, ki * lr);
        kr = t;
    }
    float cr = 0.0f, ci = 0.0f;
#pragma unroll 4
    for (int c = 0; c < NC; ++c) {
        size_t idx = ((size_t)b * NC + c) * NDIM + n;
        carRe[idx] = cr;
        carIm[idx] = ci;
        float fr = finRe[idx];
        float fi = finIm[idx];
        float t = fmaf(kr, cr, fmaf(-ki, ci, fr));
        ci = fmaf(kr, ci, fmaf(ki, cr, fi));
        cr = t;
    }
}

// ---------------------------------------------------------------------------
// Kernel S2: redo scan per chunk with correct carry; overwrite Bu planes with
// the final states (in-place is safe: each element read then written once).
// ---------------------------------------------------------------------------
__launch_bounds__(256)
__global__ void k_scan2(float* __restrict__ buRe,
                        float* __restrict__ buIm,
                        const float* __restrict__ lamRe,
                        const float* __restrict__ lamIm,
                        const float* __restrict__ carRe,
                        const float* __restrict__ carIm) {
    const int c = blockIdx.x;
    const int b = blockIdx.y;
    const int n = threadIdx.x;
    const float lr = lamRe[n];
    const float li = lamIm[n];
    size_t fidx = ((size_t)b * NC + c) * NDIM + n;
    float sr = carRe[fidx];
    float si = carIm[fidx];
    size_t base = ((size_t)b * LSEQ + (size_t)c * CH) * NDIM + n;
#pragma unroll 8
    for (int i = 0; i < CH; ++i) {
        float ur = buRe[base + (size_t)i * NDIM];
        float ui = buIm[base + (size_t)i * NDIM];
        float nr = fmaf(lr, sr, fmaf(-li, si, ur));
        float ni = fmaf(lr, si, fmaf(li, sr, ui));
        sr = nr; si = ni;
        buRe[base + (size_t)i * NDIM] = sr;
        buIm[base + (size_t)i * NDIM] = si;
    }
}

// ---------------------------------------------------------------------------
// Kernel G2: y = states_re @ Cre^T - states_im @ Cim^T + x * D
// states planes: [M, N]. Cre/Cim: [H, N] row-major (dot over n).
// ---------------------------------------------------------------------------
__launch_bounds__(256)
__global__ void k_out(const float* __restrict__ sRe,
                      const float* __restrict__ sIm,
                      const float* __restrict__ Cre,
                      const float* __restrict__ Cim,
                      const float* __restrict__ x,
                      const float* __restrict__ D,
                      float* __restrict__ y) {
    __shared__ float A1s[64][17];
    __shared__ float A2s[64][17];
    __shared__ float W1s[64][17];
    __shared__ float W2s[64][17];

    const int tid = threadIdx.x;
    const int tx = tid & 15;          // h direction
    const int ty = tid >> 4;          // m direction
    const int m0 = blockIdx.x * 64;
    const int h0 = blockIdx.y * 64;

    const int lr = tid >> 2;
    const int lc = (tid & 3) * 4;

    float acc[4][4] = {};

    for (int k0 = 0; k0 < NDIM; k0 += 16) {
        float4 a14 = *(const float4*)(sRe + (size_t)(m0 + lr) * NDIM + k0 + lc);
        float4 a24 = *(const float4*)(sIm + (size_t)(m0 + lr) * NDIM + k0 + lc);
        float4 w14 = *(const float4*)(Cre + (size_t)(h0 + lr) * NDIM + k0 + lc);
        float4 w24 = *(const float4*)(Cim + (size_t)(h0 + lr) * NDIM + k0 + lc);
        __syncthreads();
        A1s[lr][lc + 0] = a14.x; A1s[lr][lc + 1] = a14.y;
        A1s[lr][lc + 2] = a14.z; A1s[lr][lc + 3] = a14.w;
        A2s[lr][lc + 0] = a24.x; A2s[lr][lc + 1] = a24.y;
        A2s[lr][lc + 2] = a24.z; A2s[lr][lc + 3] = a24.w;
        W1s[lr][lc + 0] = w14.x; W1s[lr][lc + 1] = w14.y;
        W1s[lr][lc + 2] = w14.z; W1s[lr][lc + 3] = w14.w;
        W2s[lr][lc + 0] = w24.x; W2s[lr][lc + 1] = w24.y;
        W2s[lr][lc + 2] = w24.z; W2s[lr][lc + 3] = w24.w;
        __syncthreads();
#pragma unroll
        for (int kk = 0; kk < 16; ++kk) {
            float a1[4], a2[4], w1[4], w2[4];
#pragma unroll
            for (int i = 0; i < 4; ++i) { a1[i] = A1s[ty * 4 + i][kk]; a2[i] = A2s[ty * 4 + i][kk]; }
#pragma unroll
            for (int j = 0; j < 4; ++j) { w1[j] = W1s[tx * 4 + j][kk]; w2[j] = W2s[tx * 4 + j][kk]; }
#pragma unroll
            for (int i = 0; i < 4; ++i)
#pragma unroll
                for (int j = 0; j < 4; ++j) {
                    acc[i][j] = fmaf(a1[i], w1[j], acc[i][j]);
                    acc[i][j] = fmaf(-a2[i], w2[j], acc[i][j]);
                }
        }
    }

    float d[4];
#pragma unroll
    for (int j = 0; j < 4; ++j) d[j] = D[h0 + tx * 4 + j];

#pragma unroll
    for (int i = 0; i < 4; ++i) {
        int m = m0 + ty * 4 + i;
        float4 xv = *(const float4*)(x + (size_t)m * HDIM + h0 + tx * 4);
        float4 o;
        o.x = fmaf(xv.x, d[0], acc[i][0]);
        o.y = fmaf(xv.y, d[1], acc[i][1]);
        o.z = fmaf(xv.z, d[2], acc[i][2]);
        o.w = fmaf(xv.w, d[3], acc[i][3]);
        *(float4*)(y + (size_t)m * HDIM + h0 + tx * 4) = o;
    }
}

// ---------------------------------------------------------------------------
extern "C" void kernel_launch(void* const* d_in, const int* in_sizes, int n_in,
                              void* d_out, int out_size, void* d_ws, size_t ws_size,
                              hipStream_t stream) {
    const float* x      = (const float*)d_in[0];
    const float* B_re   = (const float*)d_in[1];
    const float* B_im   = (const float*)d_in[2];
    const float* C_re   = (const float*)d_in[3];
    const float* C_im   = (const float*)d_in[4];
    const float* nu_log = (const float*)d_in[5];
    const float* th_log = (const float*)d_in[6];
    const float* D      = (const float*)d_in[7];
    float* y = (float*)d_out;

    // Workspace layout (floats)
    float* ws    = (float*)d_ws;
    float* buRe  = ws;                                  // M*N
    float* buIm  = buRe + (size_t)MROWS * NDIM;         // M*N
    float* lamRe = buIm + (size_t)MROWS * NDIM;         // N
    float* lamIm = lamRe + NDIM;                        // N
    float* gam   = lamIm + NDIM;                        // N
    float* finRe = gam + NDIM;                          // B*NC*N
    float* finIm = finRe + (size_t)B_SZ * NC * NDIM;
    float* carRe = finIm + (size_t)B_SZ * NC * NDIM;
    float* carIm = carRe + (size_t)B_SZ * NC * NDIM;

    k_params<<<1, NDIM, 0, stream>>>(nu_log, th_log, lamRe, lamIm, gam);

    dim3 gGemm(MROWS / 64, NDIM / 64);
    k_bu<<<gGemm, 256, 0, stream>>>(x, B_re, B_im, gam, buRe, buIm);

    dim3 gScan(NC, B_SZ);
    k_scan1<<<gScan, NDIM, 0, stream>>>(buRe, buIm, lamRe, lamIm, finRe, finIm);

    k_carry<<<B_SZ, NDIM, 0, stream>>>(lamRe, lamIm, finRe, finIm, carRe, carIm);

    k_scan2<<<gScan, NDIM, 0, stream>>>(buRe, buIm, lamRe, lamIm, carRe, carIm);

    dim3 gOut(MROWS / 64, HDIM / 64);
    k_out<<<gOut, 256, 0, stream>>>(buRe, buIm, C_re, C_im, x, D, y);
}

// Round 2
// 352.271 us; speedup vs baseline: 1.3096x; 1.3096x over previous
//
#include <hip/hip_runtime.h>
#include <hip/hip_bf16.h>
#include <math.h>

// Problem constants
#define B_SZ 8
#define LSEQ 4096
#define NDIM 256
#define HDIM 256
#define MROWS (B_SZ * LSEQ)     // 32768
#define CH 64                   // chunk length for the scan
#define NC (LSEQ / CH)          // 64 chunks

// LDS tile row stride (floats): 68*4=272 B -> 16B aligned, 2-way-only bank
// aliasing on both transposed writes and b128 reads (2-way is free, m136).
#define LSTR 68

// ---------------------------------------------------------------------------
// Kernel P: compute Lambda (re/im) and gamma from nu_log / theta_log
// ---------------------------------------------------------------------------
__global__ void k_params(const float* __restrict__ nu_log,
                         const float* __restrict__ th_log,
                         float* __restrict__ lamRe,
                         float* __restrict__ lamIm,
                         float* __restrict__ gam) {
    int n = threadIdx.x;  // 256 threads
    float nu  = expf(nu_log[n]);
    float th  = expf(th_log[n]);
    float mod = expf(-nu);
    lamRe[n] = mod * cosf(th);
    lamIm[n] = mod * sinf(th);
    gam[n]   = sqrtf(fmaxf(1.0f - mod * mod, 0.0f));
}

// ---------------------------------------------------------------------------
// Kernel G1: Bu = x @ B_norm^T   (two real planes, scaled by gamma[n])
// x: [M, H] row-major.  Bre/Bim: [N, H] row-major (dot over h).
// LDS tiles stored TRANSPOSED: T[k][row], so fragment reads are ds_read_b128.
// Tile 64(m) x 64(n), 256 threads, 4x4 per thread, K-tile 16.
// ---------------------------------------------------------------------------
__launch_bounds__(256)
__global__ void k_bu(const float* __restrict__ x,
                     const float* __restrict__ Bre,
                     const float* __restrict__ Bim,
                     const float* __restrict__ gam,
                     float* __restrict__ buRe,
                     float* __restrict__ buIm) {
    __shared__ float As[16][LSTR];   // [k][m]
    __shared__ float W1s[16][LSTR];  // [k][n]
    __shared__ float W2s[16][LSTR];

    const int tid = threadIdx.x;
    const int tx = tid & 15;          // n direction
    const int ty = tid >> 4;          // m direction
    const int m0 = blockIdx.x * 64;
    const int n0 = blockIdx.y * 64;

    const int lr = tid >> 2;          // 0..63 : row within tile
    const int lc = (tid & 3) * 4;     // 0,4,8,12 : k within k-tile

    float acc1[4][4] = {};
    float acc2[4][4] = {};

    for (int k0 = 0; k0 < HDIM; k0 += 16) {
        float4 a4  = *(const float4*)(x   + (size_t)(m0 + lr) * HDIM + k0 + lc);
        float4 w14 = *(const float4*)(Bre + (size_t)(n0 + lr) * HDIM + k0 + lc);
        float4 w24 = *(const float4*)(Bim + (size_t)(n0 + lr) * HDIM + k0 + lc);
        __syncthreads();
        As[lc + 0][lr] = a4.x;  As[lc + 1][lr] = a4.y;
        As[lc + 2][lr] = a4.z;  As[lc + 3][lr] = a4.w;
        W1s[lc + 0][lr] = w14.x; W1s[lc + 1][lr] = w14.y;
        W1s[lc + 2][lr] = w14.z; W1s[lc + 3][lr] = w14.w;
        W2s[lc + 0][lr] = w24.x; W2s[lc + 1][lr] = w24.y;
        W2s[lc + 2][lr] = w24.z; W2s[lc + 3][lr] = w24.w;
        __syncthreads();
#pragma unroll
        for (int kk = 0; kk < 16; ++kk) {
            float4 av  = *(const float4*)&As[kk][ty * 4];
            float4 w1v = *(const float4*)&W1s[kk][tx * 4];
            float4 w2v = *(const float4*)&W2s[kk][tx * 4];
            float a[4]  = {av.x, av.y, av.z, av.w};
            float w1[4] = {w1v.x, w1v.y, w1v.z, w1v.w};
            float w2[4] = {w2v.x, w2v.y, w2v.z, w2v.w};
#pragma unroll
            for (int i = 0; i < 4; ++i)
#pragma unroll
                for (int j = 0; j < 4; ++j) {
                    acc1[i][j] = fmaf(a[i], w1[j], acc1[i][j]);
                    acc2[i][j] = fmaf(a[i], w2[j], acc2[i][j]);
                }
        }
    }

    float g[4];
#pragma unroll
    for (int j = 0; j < 4; ++j) g[j] = gam[n0 + tx * 4 + j];

#pragma unroll
    for (int i = 0; i < 4; ++i) {
        int m = m0 + ty * 4 + i;
        float4 o1, o2;
        o1.x = acc1[i][0] * g[0]; o1.y = acc1[i][1] * g[1];
        o1.z = acc1[i][2] * g[2]; o1.w = acc1[i][3] * g[3];
        o2.x = acc2[i][0] * g[0]; o2.y = acc2[i][1] * g[1];
        o2.z = acc2[i][2] * g[2]; o2.w = acc2[i][3] * g[3];
        *(float4*)(buRe + (size_t)m * NDIM + n0 + tx * 4) = o1;
        *(float4*)(buIm + (size_t)m * NDIM + n0 + tx * 4) = o2;
    }
}

// ---------------------------------------------------------------------------
// Kernel S1: per-chunk local scan, s starts at 0; store chunk-final state.
// grid (NC, B_SZ), block 256 (one thread per n).
// ---------------------------------------------------------------------------
__launch_bounds__(256)
__global__ void k_scan1(const float* __restrict__ buRe,
                        const float* __restrict__ buIm,
                        const float* __restrict__ lamRe,
                        const float* __restrict__ lamIm,
                        float* __restrict__ finRe,
                        float* __restrict__ finIm) {
    const int c = blockIdx.x;
    const int b = blockIdx.y;
    const int n = threadIdx.x;
    const float lr = lamRe[n];
    const float li = lamIm[n];
    size_t base = ((size_t)b * LSEQ + (size_t)c * CH) * NDIM + n;
    float sr = 0.0f, si = 0.0f;
#pragma unroll 8
    for (int i = 0; i < CH; ++i) {
        float ur = buRe[base + (size_t)i * NDIM];
        float ui = buIm[base + (size_t)i * NDIM];
        float nr = fmaf(lr, sr, fmaf(-li, si, ur));
        float ni = fmaf(lr, si, fmaf(li, sr, ui));
        sr = nr; si = ni;
    }
    size_t fidx = ((size_t)b * NC + c) * NDIM + n;
    finRe[fidx] = sr;
    finIm[fidx] = si;
}

// ---------------------------------------------------------------------------
// Kernel C2: sequential prefix over chunk carries.
// carry[b][c] = state at end of chunk c-1 (carry[b][0] = 0).
// grid B_SZ blocks, 256 threads (one per n).
// ---------------------------------------------------------------------------
__launch_bounds__(256)
__global__ void k_carry(const float* __restrict__ lamRe,
                        const float* __restrict__ lamIm,
                        const float* __restrict__ finRe,
                        const float* __restrict__ finIm,
                        float* __restrict__ carRe,
                        float* __restrict__ carIm) {
    const int b = blockIdx.x;
    const int n = threadIdx.x;
    const float lr = lamRe[n];
    const float li = lamIm[n];
    // lamK = Lambda^CH
    float kr = 1.0f, ki = 0.0f;
#pragma unroll
    for (int i = 0; i < CH; ++i) {
        float t = kr * lr - ki * li;
        ki = fmaf(kr, li, ki * lr);
        kr = t;
    }
    float cr = 0.0f, ci = 0.0f;
#pragma unroll 4
    for (int c = 0; c < NC; ++c) {
        size_t idx = ((size_t)b * NC + c) * NDIM + n;
        carRe[idx] = cr;
        carIm[idx] = ci;
        float fr = finRe[idx];
        float fi = finIm[idx];
        float t = fmaf(kr, cr, fmaf(-ki, ci, fr));
        ci = fmaf(kr, ci, fmaf(ki, cr, fi));
        cr = t;
    }
}

// ---------------------------------------------------------------------------
// Kernel S2: redo scan per chunk with correct carry; overwrite Bu planes with
// the final states (in-place is safe: each element read then written once).
// ---------------------------------------------------------------------------
__launch_bounds__(256)
__global__ void k_scan2(float* __restrict__ buRe,
                        float* __restrict__ buIm,
                        const float* __restrict__ lamRe,
                        const float* __restrict__ lamIm,
                        const float* __restrict__ carRe,
                        const float* __restrict__ carIm) {
    const int c = blockIdx.x;
    const int b = blockIdx.y;
    const int n = threadIdx.x;
    const float lr = lamRe[n];
    const float li = lamIm[n];
    size_t fidx = ((size_t)b * NC + c) * NDIM + n;
    float sr = carRe[fidx];
    float si = carIm[fidx];
    size_t base = ((size_t)b * LSEQ + (size_t)c * CH) * NDIM + n;
#pragma unroll 8
    for (int i = 0; i < CH; ++i) {
        float ur = buRe[base + (size_t)i * NDIM];
        float ui = buIm[base + (size_t)i * NDIM];
        float nr = fmaf(lr, sr, fmaf(-li, si, ur));
        float ni = fmaf(lr, si, fmaf(li, sr, ui));
        sr = nr; si = ni;
        buRe[base + (size_t)i * NDIM] = sr;
        buIm[base + (size_t)i * NDIM] = si;
    }
}

// ---------------------------------------------------------------------------
// Kernel G2: y = states_re @ Cre^T - states_im @ Cim^T + x * D
// states planes: [M, N]. Cre/Cim: [H, N] row-major (dot over n).
// LDS tiles transposed as in k_bu.
// ---------------------------------------------------------------------------
__launch_bounds__(256)
__global__ void k_out(const float* __restrict__ sRe,
                      const float* __restrict__ sIm,
                      const float* __restrict__ Cre,
                      const float* __restrict__ Cim,
                      const float* __restrict__ x,
                      const float* __restrict__ D,
                      float* __restrict__ y) {
    __shared__ float A1s[16][LSTR];
    __shared__ float A2s[16][LSTR];
    __shared__ float W1s[16][LSTR];
    __shared__ float W2s[16][LSTR];

    const int tid = threadIdx.x;
    const int tx = tid & 15;          // h direction
    const int ty = tid >> 4;          // m direction
    const int m0 = blockIdx.x * 64;
    const int h0 = blockIdx.y * 64;

    const int lr = tid >> 2;
    const int lc = (tid & 3) * 4;

    float acc[4][4] = {};

    for (int k0 = 0; k0 < NDIM; k0 += 16) {
        float4 a14 = *(const float4*)(sRe + (size_t)(m0 + lr) * NDIM + k0 + lc);
        float4 a24 = *(const float4*)(sIm + (size_t)(m0 + lr) * NDIM + k0 + lc);
        float4 w14 = *(const float4*)(Cre + (size_t)(h0 + lr) * NDIM + k0 + lc);
        float4 w24 = *(const float4*)(Cim + (size_t)(h0 + lr) * NDIM + k0 + lc);
        __syncthreads();
        A1s[lc + 0][lr] = a14.x; A1s[lc + 1][lr] = a14.y;
        A1s[lc + 2][lr] = a14.z; A1s[lc + 3][lr] = a14.w;
        A2s[lc + 0][lr] = a24.x; A2s[lc + 1][lr] = a24.y;
        A2s[lc + 2][lr] = a24.z; A2s[lc + 3][lr] = a24.w;
        W1s[lc + 0][lr] = w14.x; W1s[lc + 1][lr] = w14.y;
        W1s[lc + 2][lr] = w14.z; W1s[lc + 3][lr] = w14.w;
        W2s[lc + 0][lr] = w24.x; W2s[lc + 1][lr] = w24.y;
        W2s[lc + 2][lr] = w24.z; W2s[lc + 3][lr] = w24.w;
        __syncthreads();
#pragma unroll
        for (int kk = 0; kk < 16; ++kk) {
            float4 a1v = *(const float4*)&A1s[kk][ty * 4];
            float4 a2v = *(const float4*)&A2s[kk][ty * 4];
            float4 w1v = *(const float4*)&W1s[kk][tx * 4];
            float4 w2v = *(const float4*)&W2s[kk][tx * 4];
            float a1[4] = {a1v.x, a1v.y, a1v.z, a1v.w};
            float a2[4] = {a2v.x, a2v.y, a2v.z, a2v.w};
            float w1[4] = {w1v.x, w1v.y, w1v.z, w1v.w};
            float w2[4] = {w2v.x, w2v.y, w2v.z, w2v.w};
#pragma unroll
            for (int i = 0; i < 4; ++i)
#pragma unroll
                for (int j = 0; j < 4; ++j) {
                    acc[i][j] = fmaf(a1[i], w1[j], acc[i][j]);
                    acc[i][j] = fmaf(-a2[i], w2[j], acc[i][j]);
                }
        }
    }

    float d[4];
#pragma unroll
    for (int j = 0; j < 4; ++j) d[j] = D[h0 + tx * 4 + j];

#pragma unroll
    for (int i = 0; i < 4; ++i) {
        int m = m0 + ty * 4 + i;
        float4 xv = *(const float4*)(x + (size_t)m * HDIM + h0 + tx * 4);
        float4 o;
        o.x = fmaf(xv.x, d[0], acc[i][0]);
        o.y = fmaf(xv.y, d[1], acc[i][1]);
        o.z = fmaf(xv.z, d[2], acc[i][2]);
        o.w = fmaf(xv.w, d[3], acc[i][3]);
        *(float4*)(y + (size_t)m * HDIM + h0 + tx * 4) = o;
    }
}

// ---------------------------------------------------------------------------
extern "C" void kernel_launch(void* const* d_in, const int* in_sizes, int n_in,
                              void* d_out, int out_size, void* d_ws, size_t ws_size,
                              hipStream_t stream) {
    const float* x      = (const float*)d_in[0];
    const float* B_re   = (const float*)d_in[1];
    const float* B_im   = (const float*)d_in[2];
    const float* C_re   = (const float*)d_in[3];
    const float* C_im   = (const float*)d_in[4];
    const float* nu_log = (const float*)d_in[5];
    const float* th_log = (const float*)d_in[6];
    const float* D      = (const float*)d_in[7];
    float* y = (float*)d_out;

    // Workspace layout (floats)
    float* ws    = (float*)d_ws;
    float* buRe  = ws;                                  // M*N
    float* buIm  = buRe + (size_t)MROWS * NDIM;         // M*N
    float* lamRe = buIm + (size_t)MROWS * NDIM;         // N
    float* lamIm = lamRe + NDIM;                        // N
    float* gam   = lamIm + NDIM;                        // N
    float* finRe = gam + NDIM;                          // B*NC*N
    float* finIm = finRe + (size_t)B_SZ * NC * NDIM;
    float* carRe = finIm + (size_t)B_SZ * NC * NDIM;
    float* carIm = carRe + (size_t)B_SZ * NC * NDIM;

    k_params<<<1, NDIM, 0, stream>>>(nu_log, th_log, lamRe, lamIm, gam);

    dim3 gGemm(MROWS / 64, NDIM / 64);
    k_bu<<<gGemm, 256, 0, stream>>>(x, B_re, B_im, gam, buRe, buIm);

    dim3 gScan(NC, B_SZ);
    k_scan1<<<gScan, NDIM, 0, stream>>>(buRe, buIm, lamRe, lamIm, finRe, finIm);

    k_carry<<<B_SZ, NDIM, 0, stream>>>(lamRe, lamIm, finRe, finIm, carRe, carIm);

    k_scan2<<<gScan, NDIM, 0, stream>>>(buRe, buIm, lamRe, lamIm, carRe, carIm);

    dim3 gOut(MROWS / 64, HDIM / 64);
    k_out<<<gOut, 256, 0, stream>>>(buRe, buIm, C_re, C_im, x, D, y);
}

// Round 3
// 203.348 us; speedup vs baseline: 2.2686x; 1.7324x over previous
//
#include <hip/hip_runtime.h>
#include <hip/hip_bf16.h>
#include <math.h>

// Problem constants
#define B_SZ 8
#define LSEQ 4096
#define NDIM 256
#define HDIM 256
#define MROWS (B_SZ * LSEQ)     // 32768
#define CH 64                   // chunk length for the scan
#define NC (LSEQ / CH)          // 64 chunks

typedef _Float16 half8 __attribute__((ext_vector_type(8)));
typedef float fx4 __attribute__((ext_vector_type(4)));

// ---------------------------------------------------------------------------
// k_prep: per-row weight conversion to fp16 with gamma folded into B, -Cim,
// plus Lambda re/im. grid 256 blocks x 256 threads.
// ---------------------------------------------------------------------------
__global__ void k_prep(const float* __restrict__ Bre, const float* __restrict__ Bim,
                       const float* __restrict__ Cre, const float* __restrict__ Cim,
                       const float* __restrict__ nu_log, const float* __restrict__ th_log,
                       _Float16* __restrict__ BreH, _Float16* __restrict__ BimH,
                       _Float16* __restrict__ CreH, _Float16* __restrict__ CimNH,
                       float* __restrict__ lamRe, float* __restrict__ lamIm) {
    int r = blockIdx.x;
    int t = threadIdx.x;
    float nu  = expf(nu_log[r]);
    float th  = expf(th_log[r]);
    float mod = expf(-nu);
    float g   = sqrtf(fmaxf(1.0f - mod * mod, 0.0f));
    if (t == 0) {
        lamRe[r] = mod * cosf(th);
        lamIm[r] = mod * sinf(th);
    }
    int i = r * 256 + t;
    BreH[i]  = (_Float16)(Bre[i] * g);
    BimH[i]  = (_Float16)(Bim[i] * g);
    CreH[i]  = (_Float16)Cre[i];
    CimNH[i] = (_Float16)(-Cim[i]);
}

// ---------------------------------------------------------------------------
// k_bu: buRe/buIm (fp16) = x(fp32->fp16) @ BreH^T / BimH^T
// Block tile 64(m) x 128(n), 256 threads = 4 waves; wave tile 32x64.
// A (x) staged through LDS fragment-packed; B-frags loaded direct from global
// (weights are L2-resident).
// MFMA 16x16x32 f16: A-frag lane L: row=L&15, k=(L>>4)*8+j
//                    B-frag lane L: col=L&15, k=(L>>4)*8+j
//                    D:      lane L: col=L&15, row=(L>>4)*4+reg
// ---------------------------------------------------------------------------
__launch_bounds__(256, 3)
__global__ void k_bu(const float* __restrict__ x,
                     const _Float16* __restrict__ BreH,
                     const _Float16* __restrict__ BimH,
                     _Float16* __restrict__ buReH,
                     _Float16* __restrict__ buImH) {
    __shared__ __align__(16) _Float16 As[64 * 32];   // fragment-packed, 4 KB

    const int tid  = threadIdx.x;
    const int lane = tid & 63;
    const int wave = tid >> 6;
    const int wr   = wave >> 1;      // 0..1 (m half)
    const int wc   = wave & 1;       // 0..1 (n half)
    const int m0   = blockIdx.x * 64;
    const int n0   = blockIdx.y * 128;

    // staging slot for this thread (one slot: 256 slots total)
    const int sSub = tid >> 6;                 // subtile 0..3
    const int sRow = sSub * 16 + (lane & 15);  // row in tile
    const int sKg  = (lane >> 4) * 8;          // k offset

    const int fCol = lane & 15;       // fragment col/row-within-16
    const int fKg  = (lane >> 4) * 8;

    fx4 accR[8], accI[8];
#pragma unroll
    for (int i = 0; i < 8; ++i) { accR[i] = (fx4)0.0f; accI[i] = (fx4)0.0f; }

    for (int k0 = 0; k0 < NDIM; k0 += 32) {
        // B fragments straight from global (L2-hot weights)
        half8 bR[4], bI[4];
#pragma unroll
        for (int sn = 0; sn < 4; ++sn) {
            int n = n0 + wc * 64 + sn * 16 + fCol;
            bR[sn] = *(const half8*)(BreH + (size_t)n * HDIM + k0 + fKg);
            bI[sn] = *(const half8*)(BimH + (size_t)n * HDIM + k0 + fKg);
        }
        // stage A (convert fp32 -> fp16, fragment-packed)
        const float* xp = x + (size_t)(m0 + sRow) * HDIM + k0 + sKg;
        float4 f0 = *(const float4*)xp;
        float4 f1 = *(const float4*)(xp + 4);
        half8 hv;
        hv[0] = (_Float16)f0.x; hv[1] = (_Float16)f0.y;
        hv[2] = (_Float16)f0.z; hv[3] = (_Float16)f0.w;
        hv[4] = (_Float16)f1.x; hv[5] = (_Float16)f1.y;
        hv[6] = (_Float16)f1.z; hv[7] = (_Float16)f1.w;
        __syncthreads();
        *(half8*)&As[(size_t)tid * 8] = hv;
        __syncthreads();
        // MFMA
#pragma unroll
        for (int sm = 0; sm < 2; ++sm) {
            half8 a = *(const half8*)&As[(size_t)((wr * 2 + sm) * 64 + lane) * 8];
#pragma unroll
            for (int sn = 0; sn < 4; ++sn) {
                accR[sm * 4 + sn] = __builtin_amdgcn_mfma_f32_16x16x32_f16(a, bR[sn], accR[sm * 4 + sn], 0, 0, 0);
                accI[sm * 4 + sn] = __builtin_amdgcn_mfma_f32_16x16x32_f16(a, bI[sn], accI[sm * 4 + sn], 0, 0, 0);
            }
        }
    }

    // epilogue: D lane L: col=L&15 (n), row=(L>>4)*4+reg (m)
    const int rBase = (lane >> 4) * 4;
#pragma unroll
    for (int sm = 0; sm < 2; ++sm) {
#pragma unroll
        for (int sn = 0; sn < 4; ++sn) {
            int n = n0 + wc * 64 + sn * 16 + fCol;
#pragma unroll
            for (int reg = 0; reg < 4; ++reg) {
                int m = m0 + wr * 32 + sm * 16 + rBase + reg;
                size_t idx = (size_t)m * NDIM + n;
                buReH[idx] = (_Float16)accR[sm * 4 + sn][reg];
                buImH[idx] = (_Float16)accI[sm * 4 + sn][reg];
            }
        }
    }
}

// ---------------------------------------------------------------------------
// k_scan1: per-chunk local scan (fp32 math, fp16 input); store chunk finals.
// ---------------------------------------------------------------------------
__launch_bounds__(256)
__global__ void k_scan1(const _Float16* __restrict__ buReH,
                        const _Float16* __restrict__ buImH,
                        const float* __restrict__ lamRe,
                        const float* __restrict__ lamIm,
                        float* __restrict__ finRe,
                        float* __restrict__ finIm) {
    const int c = blockIdx.x;
    const int b = blockIdx.y;
    const int n = threadIdx.x;
    const float lr = lamRe[n];
    const float li = lamIm[n];
    size_t base = ((size_t)b * LSEQ + (size_t)c * CH) * NDIM + n;
    float sr = 0.0f, si = 0.0f;
#pragma unroll 8
    for (int i = 0; i < CH; ++i) {
        float ur = (float)buReH[base + (size_t)i * NDIM];
        float ui = (float)buImH[base + (size_t)i * NDIM];
        float nr = fmaf(lr, sr, fmaf(-li, si, ur));
        float ni = fmaf(lr, si, fmaf(li, sr, ui));
        sr = nr; si = ni;
    }
    size_t fidx = ((size_t)b * NC + c) * NDIM + n;
    finRe[fidx] = sr;
    finIm[fidx] = si;
}

// ---------------------------------------------------------------------------
// k_carry: sequential prefix over chunk carries (fp32).
// ---------------------------------------------------------------------------
__launch_bounds__(256)
__global__ void k_carry(const float* __restrict__ lamRe,
                        const float* __restrict__ lamIm,
                        const float* __restrict__ finRe,
                        const float* __restrict__ finIm,
                        float* __restrict__ carRe,
                        float* __restrict__ carIm) {
    const int b = blockIdx.x;
    const int n = threadIdx.x;
    const float lr = lamRe[n];
    const float li = lamIm[n];
    float kr = 1.0f, ki = 0.0f;
#pragma unroll
    for (int i = 0; i < CH; ++i) {
        float t = kr * lr - ki * li;
        ki = fmaf(kr, li, ki * lr);
        kr = t;
    }
    float cr = 0.0f, ci = 0.0f;
    for (int c = 0; c < NC; ++c) {
        size_t idx = ((size_t)b * NC + c) * NDIM + n;
        carRe[idx] = cr;
        carIm[idx] = ci;
        float fr = finRe[idx];
        float fi = finIm[idx];
        float t = fmaf(kr, cr, fmaf(-ki, ci, fr));
        ci = fmaf(kr, ci, fmaf(ki, cr, fi));
        cr = t;
    }
}

// ---------------------------------------------------------------------------
// k_scan2: redo scan with carry; overwrite bu planes with states (fp16).
// ---------------------------------------------------------------------------
__launch_bounds__(256)
__global__ void k_scan2(_Float16* __restrict__ buReH,
                        _Float16* __restrict__ buImH,
                        const float* __restrict__ lamRe,
                        const float* __restrict__ lamIm,
                        const float* __restrict__ carRe,
                        const float* __restrict__ carIm) {
    const int c = blockIdx.x;
    const int b = blockIdx.y;
    const int n = threadIdx.x;
    const float lr = lamRe[n];
    const float li = lamIm[n];
    size_t fidx = ((size_t)b * NC + c) * NDIM + n;
    float sr = carRe[fidx];
    float si = carIm[fidx];
    size_t base = ((size_t)b * LSEQ + (size_t)c * CH) * NDIM + n;
#pragma unroll 8
    for (int i = 0; i < CH; ++i) {
        float ur = (float)buReH[base + (size_t)i * NDIM];
        float ui = (float)buImH[base + (size_t)i * NDIM];
        float nr = fmaf(lr, sr, fmaf(-li, si, ur));
        float ni = fmaf(lr, si, fmaf(li, sr, ui));
        sr = nr; si = ni;
        buReH[base + (size_t)i * NDIM] = (_Float16)sr;
        buImH[base + (size_t)i * NDIM] = (_Float16)si;
    }
}

// ---------------------------------------------------------------------------
// k_out: y(fp32) = sReH @ CreH^T + sImH @ CimNH^T + x*D
// (CimNH pre-negated). Same tiling as k_bu; two A planes staged in LDS.
// ---------------------------------------------------------------------------
__launch_bounds__(256, 3)
__global__ void k_out(const _Float16* __restrict__ sReH,
                      const _Float16* __restrict__ sImH,
                      const _Float16* __restrict__ CreH,
                      const _Float16* __restrict__ CimNH,
                      const float* __restrict__ x,
                      const float* __restrict__ Dv,
                      float* __restrict__ y) {
    __shared__ __align__(16) _Float16 A1[64 * 32];
    __shared__ __align__(16) _Float16 A2[64 * 32];

    const int tid  = threadIdx.x;
    const int lane = tid & 63;
    const int wave = tid >> 6;
    const int wr   = wave >> 1;
    const int wc   = wave & 1;
    const int m0   = blockIdx.x * 64;
    const int h0   = blockIdx.y * 128;

    const int sSub = tid >> 6;
    const int sRow = sSub * 16 + (lane & 15);
    const int sKg  = (lane >> 4) * 8;

    const int fCol = lane & 15;
    const int fKg  = (lane >> 4) * 8;

    fx4 acc[8];
#pragma unroll
    for (int i = 0; i < 8; ++i) acc[i] = (fx4)0.0f;

    for (int k0 = 0; k0 < NDIM; k0 += 32) {
        half8 bR[4], bI[4];
#pragma unroll
        for (int sn = 0; sn < 4; ++sn) {
            int h = h0 + wc * 64 + sn * 16 + fCol;
            bR[sn] = *(const half8*)(CreH  + (size_t)h * NDIM + k0 + fKg);
            bI[sn] = *(const half8*)(CimNH + (size_t)h * NDIM + k0 + fKg);
        }
        size_t gOff = (size_t)(m0 + sRow) * NDIM + k0 + sKg;
        half8 h1 = *(const half8*)(sReH + gOff);
        half8 h2 = *(const half8*)(sImH + gOff);
        __syncthreads();
        *(half8*)&A1[(size_t)tid * 8] = h1;
        *(half8*)&A2[(size_t)tid * 8] = h2;
        __syncthreads();
#pragma unroll
        for (int sm = 0; sm < 2; ++sm) {
            half8 a1 = *(const half8*)&A1[(size_t)((wr * 2 + sm) * 64 + lane) * 8];
            half8 a2 = *(const half8*)&A2[(size_t)((wr * 2 + sm) * 64 + lane) * 8];
#pragma unroll
            for (int sn = 0; sn < 4; ++sn) {
                acc[sm * 4 + sn] = __builtin_amdgcn_mfma_f32_16x16x32_f16(a1, bR[sn], acc[sm * 4 + sn], 0, 0, 0);
                acc[sm * 4 + sn] = __builtin_amdgcn_mfma_f32_16x16x32_f16(a2, bI[sn], acc[sm * 4 + sn], 0, 0, 0);
            }
        }
    }

    float d[4];
#pragma unroll
    for (int sn = 0; sn < 4; ++sn) d[sn] = Dv[h0 + wc * 64 + sn * 16 + fCol];

    const int rBase = (lane >> 4) * 4;
#pragma unroll
    for (int sm = 0; sm < 2; ++sm) {
#pragma unroll
        for (int sn = 0; sn < 4; ++sn) {
            int h = h0 + wc * 64 + sn * 16 + fCol;
#pragma unroll
            for (int reg = 0; reg < 4; ++reg) {
                int m = m0 + wr * 32 + sm * 16 + rBase + reg;
                size_t idx = (size_t)m * HDIM + h;
                y[idx] = fmaf(x[idx], d[sn], acc[sm * 4 + sn][reg]);
            }
        }
    }
}

// ---------------------------------------------------------------------------
extern "C" void kernel_launch(void* const* d_in, const int* in_sizes, int n_in,
                              void* d_out, int out_size, void* d_ws, size_t ws_size,
                              hipStream_t stream) {
    const float* x      = (const float*)d_in[0];
    const float* B_re   = (const float*)d_in[1];
    const float* B_im   = (const float*)d_in[2];
    const float* C_re   = (const float*)d_in[3];
    const float* C_im   = (const float*)d_in[4];
    const float* nu_log = (const float*)d_in[5];
    const float* th_log = (const float*)d_in[6];
    const float* D      = (const float*)d_in[7];
    float* y = (float*)d_out;

    // Workspace layout
    char* p = (char*)d_ws;
    _Float16* buReH = (_Float16*)p;  p += (size_t)MROWS * NDIM * 2;
    _Float16* buImH = (_Float16*)p;  p += (size_t)MROWS * NDIM * 2;
    _Float16* BreH  = (_Float16*)p;  p += (size_t)NDIM * HDIM * 2;
    _Float16* BimH  = (_Float16*)p;  p += (size_t)NDIM * HDIM * 2;
    _Float16* CreH  = (_Float16*)p;  p += (size_t)HDIM * NDIM * 2;
    _Float16* CimNH = (_Float16*)p;  p += (size_t)HDIM * NDIM * 2;
    float* lamRe = (float*)p;  p += NDIM * 4;
    float* lamIm = (float*)p;  p += NDIM * 4;
    float* finRe = (float*)p;  p += (size_t)B_SZ * NC * NDIM * 4;
    float* finIm = (float*)p;  p += (size_t)B_SZ * NC * NDIM * 4;
    float* carRe = (float*)p;  p += (size_t)B_SZ * NC * NDIM * 4;
    float* carIm = (float*)p;  p += (size_t)B_SZ * NC * NDIM * 4;

    k_prep<<<NDIM, 256, 0, stream>>>(B_re, B_im, C_re, C_im, nu_log, th_log,
                                     BreH, BimH, CreH, CimNH, lamRe, lamIm);

    dim3 gGemm(MROWS / 64, NDIM / 128);
    k_bu<<<gGemm, 256, 0, stream>>>(x, BreH, BimH, buReH, buImH);

    dim3 gScan(NC, B_SZ);
    k_scan1<<<gScan, 256, 0, stream>>>(buReH, buImH, lamRe, lamIm, finRe, finIm);

    k_carry<<<B_SZ, 256, 0, stream>>>(lamRe, lamIm, finRe, finIm, carRe, carIm);

    k_scan2<<<gScan, 256, 0, stream>>>(buReH, buImH, lamRe, lamIm, carRe, carIm);

    dim3 gOut(MROWS / 64, HDIM / 128);
    k_out<<<gOut, 256, 0, stream>>>(buReH, buImH, CreH, CimNH, x, D, y);
}

// Round 4
// 171.835 us; speedup vs baseline: 2.6847x; 1.1834x over previous
//
#include <hip/hip_runtime.h>
#include <hip/hip_bf16.h>
#include <math.h>

// Problem constants
#define B_SZ 8
#define LSEQ 4096
#define NDIM 256
#define HDIM 256
#define MROWS (B_SZ * LSEQ)     // 32768
#define CH 64                   // chunk length (== GEMM m-tile, aligned)
#define NC (LSEQ / CH)          // 64 chunks per batch

#define BM 64
#define BN 128
#define BK 32
#define PAD 40                  // LDS row stride in halfs (80 B -> 2-way max)

typedef _Float16 half8 __attribute__((ext_vector_type(8)));
typedef float fx4 __attribute__((ext_vector_type(4)));

// ---------------------------------------------------------------------------
// k_prep: weights -> fp16 (gamma folded into B, Cim negated), Lambda re/im.
// grid 256 x 256.
// ---------------------------------------------------------------------------
__global__ void k_prep(const float* __restrict__ Bre, const float* __restrict__ Bim,
                       const float* __restrict__ Cre, const float* __restrict__ Cim,
                       const float* __restrict__ nu_log, const float* __restrict__ th_log,
                       _Float16* __restrict__ BreH, _Float16* __restrict__ BimH,
                       _Float16* __restrict__ CreH, _Float16* __restrict__ CimNH,
                       float* __restrict__ lamRe, float* __restrict__ lamIm) {
    int r = blockIdx.x;
    int t = threadIdx.x;
    float nu  = expf(nu_log[r]);
    float th  = expf(th_log[r]);
    float mod = expf(-nu);
    float g   = sqrtf(fmaxf(1.0f - mod * mod, 0.0f));
    if (t == 0) {
        lamRe[r] = mod * cosf(th);
        lamIm[r] = mod * sinf(th);
    }
    int i = r * 256 + t;
    BreH[i]  = (_Float16)(Bre[i] * g);
    BimH[i]  = (_Float16)(Bim[i] * g);
    CreH[i]  = (_Float16)Cre[i];
    CimNH[i] = (_Float16)(-Cim[i]);
}

// ---------------------------------------------------------------------------
// k_pow: pow table P[i][n] = Lambda[n]^(i+1), computed from polar form.
// grid CH x 256.
// ---------------------------------------------------------------------------
__global__ void k_pow(const float* __restrict__ nu_log, const float* __restrict__ th_log,
                      float* __restrict__ powRe, float* __restrict__ powIm) {
    int i = blockIdx.x;
    int n = threadIdx.x;
    float nu = expf(nu_log[n]);
    float th = expf(th_log[n]);
    float k  = (float)(i + 1);
    float mod = expf(-nu * k);
    powRe[i * 256 + n] = mod * cosf(th * k);
    powIm[i * 256 + n] = mod * sinf(th * k);
}

// ---------------------------------------------------------------------------
// k_bu: buRe/buIm (fp16) = x @ BreH^T / BimH^T.  64m x 128n block, 4 waves
// (wave tile 32m x 64n), BK=32, double-buffered LDS, 1 barrier/iter.
// MFMA 16x16x32 f16 mappings (verified m89/m91):
//   A/B frag lane L: row/col = L&15, k = (L>>4)*8 + j
//   D lane L: col = L&15, row = (L>>4)*4 + reg
// ---------------------------------------------------------------------------
__launch_bounds__(256)
__global__ void k_bu(const float* __restrict__ x,
                     const _Float16* __restrict__ BreH,
                     const _Float16* __restrict__ BimH,
                     _Float16* __restrict__ buReH,
                     _Float16* __restrict__ buImH) {
    __shared__ __align__(16) _Float16 As[2][BM * PAD];   // 5120 B each
    __shared__ __align__(16) _Float16 Br[2][BN * PAD];   // 10240 B each
    __shared__ __align__(16) _Float16 Bi[2][BN * PAD];

    const int tid  = threadIdx.x;
    const int lane = tid & 63;
    const int wave = tid >> 6;
    const int wr   = wave >> 1;
    const int wc   = wave & 1;
    const int m0   = blockIdx.x * BM;
    const int n0   = blockIdx.y * BN;

    // A staging map: row = tid>>2 (0..63), cols (tid&3)*8 .. +7
    const int ar = tid >> 2, ac = (tid & 3) * 8;
    // B staging map: nrow = tid>>1 (0..127), cols (tid&1)*16 .. +15
    const int br = tid >> 1, bc = (tid & 1) * 16;

    const int fRC = lane & 15;
    const int fKg = (lane >> 4) * 8;

    fx4 accR[8], accI[8];
#pragma unroll
    for (int i = 0; i < 8; ++i) { accR[i] = (fx4)0.0f; accI[i] = (fx4)0.0f; }

    // staging registers
    float4 xf0, xf1;
    half8 wr0, wr1, wi0, wi1;

    // prologue: load + write k0=0 into buf 0
    {
        const float* xp = x + (size_t)(m0 + ar) * HDIM + ac;
        xf0 = *(const float4*)xp;
        xf1 = *(const float4*)(xp + 4);
        const _Float16* bp1 = BreH + (size_t)(n0 + br) * HDIM + bc;
        const _Float16* bp2 = BimH + (size_t)(n0 + br) * HDIM + bc;
        wr0 = *(const half8*)bp1;       wr1 = *(const half8*)(bp1 + 8);
        wi0 = *(const half8*)bp2;       wi1 = *(const half8*)(bp2 + 8);
        half8 hv;
        hv[0]=(_Float16)xf0.x; hv[1]=(_Float16)xf0.y; hv[2]=(_Float16)xf0.z; hv[3]=(_Float16)xf0.w;
        hv[4]=(_Float16)xf1.x; hv[5]=(_Float16)xf1.y; hv[6]=(_Float16)xf1.z; hv[7]=(_Float16)xf1.w;
        *(half8*)&As[0][ar * PAD + ac] = hv;
        *(half8*)&Br[0][br * PAD + bc] = wr0;  *(half8*)&Br[0][br * PAD + bc + 8] = wr1;
        *(half8*)&Bi[0][br * PAD + bc] = wi0;  *(half8*)&Bi[0][br * PAD + bc + 8] = wi1;
    }
    __syncthreads();

    int p = 0;
    for (int k0 = 0; k0 < HDIM; k0 += BK) {
        const bool nx = (k0 + BK) < HDIM;
        if (nx) {  // issue next tile's global loads (overlap with MFMA below)
            const float* xp = x + (size_t)(m0 + ar) * HDIM + k0 + BK + ac;
            xf0 = *(const float4*)xp;
            xf1 = *(const float4*)(xp + 4);
            const _Float16* bp1 = BreH + (size_t)(n0 + br) * HDIM + k0 + BK + bc;
            const _Float16* bp2 = BimH + (size_t)(n0 + br) * HDIM + k0 + BK + bc;
            wr0 = *(const half8*)bp1;   wr1 = *(const half8*)(bp1 + 8);
            wi0 = *(const half8*)bp2;   wi1 = *(const half8*)(bp2 + 8);
        }
        // fragments from buf p
        half8 af[2], bRf[4], bIf[4];
#pragma unroll
        for (int sm = 0; sm < 2; ++sm)
            af[sm] = *(const half8*)&As[p][(wr * 32 + sm * 16 + fRC) * PAD + fKg];
#pragma unroll
        for (int sn = 0; sn < 4; ++sn) {
            bRf[sn] = *(const half8*)&Br[p][(wc * 64 + sn * 16 + fRC) * PAD + fKg];
            bIf[sn] = *(const half8*)&Bi[p][(wc * 64 + sn * 16 + fRC) * PAD + fKg];
        }
#pragma unroll
        for (int sm = 0; sm < 2; ++sm)
#pragma unroll
            for (int sn = 0; sn < 4; ++sn) {
                accR[sm * 4 + sn] = __builtin_amdgcn_mfma_f32_16x16x32_f16(af[sm], bRf[sn], accR[sm * 4 + sn], 0, 0, 0);
                accI[sm * 4 + sn] = __builtin_amdgcn_mfma_f32_16x16x32_f16(af[sm], bIf[sn], accI[sm * 4 + sn], 0, 0, 0);
            }
        if (nx) {
            int pn = p ^ 1;
            half8 hv;
            hv[0]=(_Float16)xf0.x; hv[1]=(_Float16)xf0.y; hv[2]=(_Float16)xf0.z; hv[3]=(_Float16)xf0.w;
            hv[4]=(_Float16)xf1.x; hv[5]=(_Float16)xf1.y; hv[6]=(_Float16)xf1.z; hv[7]=(_Float16)xf1.w;
            *(half8*)&As[pn][ar * PAD + ac] = hv;
            *(half8*)&Br[pn][br * PAD + bc] = wr0;  *(half8*)&Br[pn][br * PAD + bc + 8] = wr1;
            *(half8*)&Bi[pn][br * PAD + bc] = wi0;  *(half8*)&Bi[pn][br * PAD + bc + 8] = wi1;
        }
        __syncthreads();
        p ^= 1;
    }

    const int rBase = (lane >> 4) * 4;
#pragma unroll
    for (int sm = 0; sm < 2; ++sm)
#pragma unroll
        for (int sn = 0; sn < 4; ++sn) {
            int n = n0 + wc * 64 + sn * 16 + fRC;
#pragma unroll
            for (int reg = 0; reg < 4; ++reg) {
                int m = m0 + wr * 32 + sm * 16 + rBase + reg;
                size_t idx = (size_t)m * NDIM + n;
                buReH[idx] = (_Float16)accR[sm * 4 + sn][reg];
                buImH[idx] = (_Float16)accI[sm * 4 + sn][reg];
            }
        }
}

// ---------------------------------------------------------------------------
// k_scan1: per-chunk local scan (fp32 math); writes local states in place
// (fp16) and chunk finals (fp32).
// ---------------------------------------------------------------------------
__launch_bounds__(256)
__global__ void k_scan1(_Float16* __restrict__ buReH,
                        _Float16* __restrict__ buImH,
                        const float* __restrict__ lamRe,
                        const float* __restrict__ lamIm,
                        float* __restrict__ finRe,
                        float* __restrict__ finIm) {
    const int c = blockIdx.x;
    const int b = blockIdx.y;
    const int n = threadIdx.x;
    const float lr = lamRe[n];
    const float li = lamIm[n];
    size_t base = ((size_t)b * LSEQ + (size_t)c * CH) * NDIM + n;
    float sr = 0.0f, si = 0.0f;
#pragma unroll 8
    for (int i = 0; i < CH; ++i) {
        size_t idx = base + (size_t)i * NDIM;
        float ur = (float)buReH[idx];
        float ui = (float)buImH[idx];
        float nr = fmaf(lr, sr, fmaf(-li, si, ur));
        float ni = fmaf(lr, si, fmaf(li, sr, ui));
        sr = nr; si = ni;
        buReH[idx] = (_Float16)sr;
        buImH[idx] = (_Float16)si;
    }
    size_t fidx = ((size_t)b * NC + c) * NDIM + n;
    finRe[fidx] = sr;
    finIm[fidx] = si;
}

// ---------------------------------------------------------------------------
// k_carry: sequential prefix over chunk finals -> carry per chunk (fp32).
// ---------------------------------------------------------------------------
__launch_bounds__(256)
__global__ void k_carry(const float* __restrict__ lamRe,
                        const float* __restrict__ lamIm,
                        const float* __restrict__ finRe,
                        const float* __restrict__ finIm,
                        float* __restrict__ carRe,
                        float* __restrict__ carIm) {
    const int b = blockIdx.x;
    const int n = threadIdx.x;
    const float lr = lamRe[n];
    const float li = lamIm[n];
    float kr = 1.0f, ki = 0.0f;
#pragma unroll
    for (int i = 0; i < CH; ++i) {
        float t = kr * lr - ki * li;
        ki = fmaf(kr, li, ki * lr);
        kr = t;
    }
    float cr = 0.0f, ci = 0.0f;
    for (int c = 0; c < NC; ++c) {
        size_t idx = ((size_t)b * NC + c) * NDIM + n;
        carRe[idx] = cr;
        carIm[idx] = ci;
        float fr = finRe[idx];
        float fi = finIm[idx];
        float t = fmaf(kr, cr, fmaf(-ki, ci, fr));
        ci = fmaf(kr, ci, fmaf(ki, cr, fi));
        cr = t;
    }
}

// ---------------------------------------------------------------------------
// k_out: y = s @ CreH^T + sIm @ CimNH^T + x*D, with the chunk carry applied
// during A-staging: state[i] = local[i] + P[i]*carry  (P = Lambda^(i+1)).
// m-tile == one chunk (64 rows), so row index == local i, chunk = m0>>6.
// ---------------------------------------------------------------------------
__launch_bounds__(256)
__global__ void k_out(const _Float16* __restrict__ sReH,
                      const _Float16* __restrict__ sImH,
                      const _Float16* __restrict__ CreH,
                      const _Float16* __restrict__ CimNH,
                      const float* __restrict__ powRe,
                      const float* __restrict__ powIm,
                      const float* __restrict__ carRe,
                      const float* __restrict__ carIm,
                      const float* __restrict__ x,
                      const float* __restrict__ Dv,
                      float* __restrict__ y) {
    __shared__ __align__(16) _Float16 A1[2][BM * PAD];
    __shared__ __align__(16) _Float16 A2[2][BM * PAD];
    __shared__ __align__(16) _Float16 Cr[2][BN * PAD];
    __shared__ __align__(16) _Float16 Ci[2][BN * PAD];

    const int tid  = threadIdx.x;
    const int lane = tid & 63;
    const int wave = tid >> 6;
    const int wr   = wave >> 1;
    const int wc   = wave & 1;
    const int m0   = blockIdx.x * BM;
    const int h0   = blockIdx.y * BN;
    const int chunk = m0 >> 6;

    const int ar = tid >> 2, ac = (tid & 3) * 8;
    const int br = tid >> 1, bc = (tid & 1) * 16;

    const int fRC = lane & 15;
    const int fKg = (lane >> 4) * 8;

    fx4 acc[8];
#pragma unroll
    for (int i = 0; i < 8; ++i) acc[i] = (fx4)0.0f;

    half8 s1, s2, c0a, c0b, c1a, c1b;
    float4 pr0, pr1, pi0, pi1, cr0, cr1, ci0, ci1;

#define LOAD_STAGE(K0)                                                          \
    {                                                                           \
        size_t aOff = (size_t)(m0 + ar) * NDIM + (K0) + ac;                     \
        s1 = *(const half8*)(sReH + aOff);                                      \
        s2 = *(const half8*)(sImH + aOff);                                      \
        size_t pOff = (size_t)ar * NDIM + (K0) + ac;                            \
        pr0 = *(const float4*)(powRe + pOff); pr1 = *(const float4*)(powRe + pOff + 4); \
        pi0 = *(const float4*)(powIm + pOff); pi1 = *(const float4*)(powIm + pOff + 4); \
        size_t cOff = (size_t)chunk * NDIM + (K0) + ac;                         \
        cr0 = *(const float4*)(carRe + cOff); cr1 = *(const float4*)(carRe + cOff + 4); \
        ci0 = *(const float4*)(carIm + cOff); ci1 = *(const float4*)(carIm + cOff + 4); \
        const _Float16* cp1 = CreH  + (size_t)(h0 + br) * NDIM + (K0) + bc;     \
        const _Float16* cp2 = CimNH + (size_t)(h0 + br) * NDIM + (K0) + bc;     \
        c0a = *(const half8*)cp1;  c0b = *(const half8*)(cp1 + 8);              \
        c1a = *(const half8*)cp2;  c1b = *(const half8*)(cp2 + 8);              \
    }

#define WRITE_STAGE(P)                                                          \
    {                                                                           \
        float prA[8] = {pr0.x,pr0.y,pr0.z,pr0.w,pr1.x,pr1.y,pr1.z,pr1.w};       \
        float piA[8] = {pi0.x,pi0.y,pi0.z,pi0.w,pi1.x,pi1.y,pi1.z,pi1.w};       \
        float crA[8] = {cr0.x,cr0.y,cr0.z,cr0.w,cr1.x,cr1.y,cr1.z,cr1.w};       \
        float ciA[8] = {ci0.x,ci0.y,ci0.z,ci0.w,ci1.x,ci1.y,ci1.z,ci1.w};       \
        half8 h1, h2;                                                           \
        _Pragma("unroll")                                                       \
        for (int e = 0; e < 8; ++e) {                                           \
            float ur = fmaf(prA[e], crA[e], fmaf(-piA[e], ciA[e], (float)s1[e])); \
            float ui = fmaf(prA[e], ciA[e], fmaf( piA[e], crA[e], (float)s2[e])); \
            h1[e] = (_Float16)ur; h2[e] = (_Float16)ui;                         \
        }                                                                       \
        *(half8*)&A1[P][ar * PAD + ac] = h1;                                    \
        *(half8*)&A2[P][ar * PAD + ac] = h2;                                    \
        *(half8*)&Cr[P][br * PAD + bc] = c0a;  *(half8*)&Cr[P][br * PAD + bc + 8] = c0b; \
        *(half8*)&Ci[P][br * PAD + bc] = c1a;  *(half8*)&Ci[P][br * PAD + bc + 8] = c1b; \
    }

    LOAD_STAGE(0);
    WRITE_STAGE(0);
    __syncthreads();

    int p = 0;
    for (int k0 = 0; k0 < NDIM; k0 += BK) {
        const bool nx = (k0 + BK) < NDIM;
        if (nx) LOAD_STAGE(k0 + BK);
        half8 a1[2], a2[2], bRf[4], bIf[4];
#pragma unroll
        for (int sm = 0; sm < 2; ++sm) {
            a1[sm] = *(const half8*)&A1[p][(wr * 32 + sm * 16 + fRC) * PAD + fKg];
            a2[sm] = *(const half8*)&A2[p][(wr * 32 + sm * 16 + fRC) * PAD + fKg];
        }
#pragma unroll
        for (int sn = 0; sn < 4; ++sn) {
            bRf[sn] = *(const half8*)&Cr[p][(wc * 64 + sn * 16 + fRC) * PAD + fKg];
            bIf[sn] = *(const half8*)&Ci[p][(wc * 64 + sn * 16 + fRC) * PAD + fKg];
        }
#pragma unroll
        for (int sm = 0; sm < 2; ++sm)
#pragma unroll
            for (int sn = 0; sn < 4; ++sn) {
                acc[sm * 4 + sn] = __builtin_amdgcn_mfma_f32_16x16x32_f16(a1[sm], bRf[sn], acc[sm * 4 + sn], 0, 0, 0);
                acc[sm * 4 + sn] = __builtin_amdgcn_mfma_f32_16x16x32_f16(a2[sm], bIf[sn], acc[sm * 4 + sn], 0, 0, 0);
            }
        if (nx) WRITE_STAGE(p ^ 1);
        __syncthreads();
        p ^= 1;
    }

    float d[4];
#pragma unroll
    for (int sn = 0; sn < 4; ++sn) d[sn] = Dv[h0 + wc * 64 + sn * 16 + fRC];

    const int rBase = (lane >> 4) * 4;
#pragma unroll
    for (int sm = 0; sm < 2; ++sm)
#pragma unroll
        for (int sn = 0; sn < 4; ++sn) {
            int h = h0 + wc * 64 + sn * 16 + fRC;
#pragma unroll
            for (int reg = 0; reg < 4; ++reg) {
                int m = m0 + wr * 32 + sm * 16 + rBase + reg;
                size_t idx = (size_t)m * HDIM + h;
                y[idx] = fmaf(x[idx], d[sn], acc[sm * 4 + sn][reg]);
            }
        }
#undef LOAD_STAGE
#undef WRITE_STAGE
}

// ---------------------------------------------------------------------------
extern "C" void kernel_launch(void* const* d_in, const int* in_sizes, int n_in,
                              void* d_out, int out_size, void* d_ws, size_t ws_size,
                              hipStream_t stream) {
    const float* x      = (const float*)d_in[0];
    const float* B_re   = (const float*)d_in[1];
    const float* B_im   = (const float*)d_in[2];
    const float* C_re   = (const float*)d_in[3];
    const float* C_im   = (const float*)d_in[4];
    const float* nu_log = (const float*)d_in[5];
    const float* th_log = (const float*)d_in[6];
    const float* D      = (const float*)d_in[7];
    float* y = (float*)d_out;

    char* p = (char*)d_ws;
    _Float16* buReH = (_Float16*)p;  p += (size_t)MROWS * NDIM * 2;
    _Float16* buImH = (_Float16*)p;  p += (size_t)MROWS * NDIM * 2;
    _Float16* BreH  = (_Float16*)p;  p += (size_t)NDIM * HDIM * 2;
    _Float16* BimH  = (_Float16*)p;  p += (size_t)NDIM * HDIM * 2;
    _Float16* CreH  = (_Float16*)p;  p += (size_t)HDIM * NDIM * 2;
    _Float16* CimNH = (_Float16*)p;  p += (size_t)HDIM * NDIM * 2;
    float* lamRe = (float*)p;  p += NDIM * 4;
    float* lamIm = (float*)p;  p += NDIM * 4;
    float* powRe = (float*)p;  p += (size_t)CH * NDIM * 4;
    float* powIm = (float*)p;  p += (size_t)CH * NDIM * 4;
    float* finRe = (float*)p;  p += (size_t)B_SZ * NC * NDIM * 4;
    float* finIm = (float*)p;  p += (size_t)B_SZ * NC * NDIM * 4;
    float* carRe = (float*)p;  p += (size_t)B_SZ * NC * NDIM * 4;
    float* carIm = (float*)p;  p += (size_t)B_SZ * NC * NDIM * 4;

    k_prep<<<NDIM, 256, 0, stream>>>(B_re, B_im, C_re, C_im, nu_log, th_log,
                                     BreH, BimH, CreH, CimNH, lamRe, lamIm);
    k_pow<<<CH, 256, 0, stream>>>(nu_log, th_log, powRe, powIm);

    dim3 gGemm(MROWS / BM, NDIM / BN);
    k_bu<<<gGemm, 256, 0, stream>>>(x, BreH, BimH, buReH, buImH);

    dim3 gScan(NC, B_SZ);
    k_scan1<<<gScan, 256, 0, stream>>>(buReH, buImH, lamRe, lamIm, finRe, finIm);

    k_carry<<<B_SZ, 256, 0, stream>>>(lamRe, lamIm, finRe, finIm, carRe, carIm);

    dim3 gOut(MROWS / BM, HDIM / BN);
    k_out<<<gOut, 256, 0, stream>>>(buReH, buImH, CreH, CimNH,
                                    powRe, powIm, carRe, carIm, x, D, y);
}

// Round 5
// 161.792 us; speedup vs baseline: 2.8513x; 1.0621x over previous
//
#include <hip/hip_runtime.h>
#include <hip/hip_bf16.h>
#include <math.h>

// Problem constants
#define B_SZ 8
#define LSEQ 4096
#define NDIM 256
#define HDIM 256
#define MROWS (B_SZ * LSEQ)     // 32768
#define CH 64                   // chunk length (== GEMM m-tile)
#define NC (LSEQ / CH)          // 64 chunks per batch

#define BM 64
#define BN 128
#define BK 32
#define PAD 40                  // GEMM LDS row stride (halfs)
#define SSTR 68                 // scan LDS col stride (halfs), 136B, 8B-aligned

typedef _Float16 half8 __attribute__((ext_vector_type(8)));
typedef _Float16 half4 __attribute__((ext_vector_type(4)));
typedef float fx4 __attribute__((ext_vector_type(4)));

// ---------------------------------------------------------------------------
// k_prep: weights -> fp16 (gamma folded into B, Cim negated), Lambda re/im,
// and pow table P[i][n] = Lambda[n]^(i+1) for blocks < CH.  grid 256 x 256.
// ---------------------------------------------------------------------------
__global__ void k_prep(const float* __restrict__ Bre, const float* __restrict__ Bim,
                       const float* __restrict__ Cre, const float* __restrict__ Cim,
                       const float* __restrict__ nu_log, const float* __restrict__ th_log,
                       _Float16* __restrict__ BreH, _Float16* __restrict__ BimH,
                       _Float16* __restrict__ CreH, _Float16* __restrict__ CimNH,
                       float* __restrict__ lamRe, float* __restrict__ lamIm,
                       float* __restrict__ powRe, float* __restrict__ powIm) {
    int r = blockIdx.x;
    int t = threadIdx.x;
    // weights row r
    float nu  = expf(nu_log[r]);
    float th  = expf(th_log[r]);
    float mod = expf(-nu);
    float g   = sqrtf(fmaxf(1.0f - mod * mod, 0.0f));
    if (t == 0) {
        lamRe[r] = mod * cosf(th);
        lamIm[r] = mod * sinf(th);
    }
    int i = r * 256 + t;
    BreH[i]  = (_Float16)(Bre[i] * g);
    BimH[i]  = (_Float16)(Bim[i] * g);
    CreH[i]  = (_Float16)Cre[i];
    CimNH[i] = (_Float16)(-Cim[i]);
    // pow row r (column n = t): Lambda[t]^(r+1)
    if (r < CH) {
        float nuN = expf(nu_log[t]);
        float thN = expf(th_log[t]);
        float k   = (float)(r + 1);
        float mo  = expf(-nuN * k);
        powRe[r * 256 + t] = mo * cosf(thN * k);
        powIm[r * 256 + t] = mo * sinf(thN * k);
    }
}

// ---------------------------------------------------------------------------
// k_buscan: fused  Bu = x @ B^T  GEMM  +  per-chunk local scan.
// Block 64m x 128n (m-tile == one chunk), 4 waves, BK=32 double-buffered LDS.
// After the K-loop the accumulators go through LDS scan buffers (unioned with
// the GEMM staging LDS) laid out [col][row]; threads 0..127 run the fp32
// per-column scan over the 64 rows, write chunk finals, then all 256 threads
// write the locally-scanned states (fp16) coalesced to global.
// MFMA 16x16x32 f16 mappings (verified m89/m91):
//   A/B frag lane L: row/col = L&15, k = (L>>4)*8 + j
//   D lane L: col = L&15, row = (L>>4)*4 + reg
// ---------------------------------------------------------------------------
__launch_bounds__(256)
__global__ void k_buscan(const float* __restrict__ x,
                         const _Float16* __restrict__ BreH,
                         const _Float16* __restrict__ BimH,
                         const float* __restrict__ lamRe,
                         const float* __restrict__ lamIm,
                         _Float16* __restrict__ stReH,
                         _Float16* __restrict__ stImH,
                         float* __restrict__ finRe,
                         float* __restrict__ finIm) {
    // 51200 B union: GEMM dbuf (25600 halfs) / scan buffers (17408 halfs)
    __shared__ __align__(16) _Float16 smem[25600];
    // GEMM layout (halfs): As p*12800+0, Br p*12800+2560, Bi p*12800+7680
    // scan layout: SRe at 0 (128*SSTR), SIm at 8704

    const int tid  = threadIdx.x;
    const int lane = tid & 63;
    const int wave = tid >> 6;
    const int wr   = wave >> 1;
    const int wc   = wave & 1;
    const int m0   = blockIdx.x * BM;
    const int n0   = blockIdx.y * BN;

    const int ar = tid >> 2, ac = (tid & 3) * 8;    // A staging map
    const int br = tid >> 1, bc = (tid & 1) * 16;   // B staging map

    const int fRC = lane & 15;
    const int fKg = (lane >> 4) * 8;

    fx4 accR[8], accI[8];
#pragma unroll
    for (int i = 0; i < 8; ++i) { accR[i] = (fx4)0.0f; accI[i] = (fx4)0.0f; }

    float4 xf0, xf1;
    half8 w0, w1, w2, w3;

    // prologue: stage k0=0 into buf 0
    {
        const float* xp = x + (size_t)(m0 + ar) * HDIM + ac;
        xf0 = *(const float4*)xp;
        xf1 = *(const float4*)(xp + 4);
        const _Float16* bp1 = BreH + (size_t)(n0 + br) * HDIM + bc;
        const _Float16* bp2 = BimH + (size_t)(n0 + br) * HDIM + bc;
        w0 = *(const half8*)bp1;  w1 = *(const half8*)(bp1 + 8);
        w2 = *(const half8*)bp2;  w3 = *(const half8*)(bp2 + 8);
        half8 hv;
        hv[0]=(_Float16)xf0.x; hv[1]=(_Float16)xf0.y; hv[2]=(_Float16)xf0.z; hv[3]=(_Float16)xf0.w;
        hv[4]=(_Float16)xf1.x; hv[5]=(_Float16)xf1.y; hv[6]=(_Float16)xf1.z; hv[7]=(_Float16)xf1.w;
        *(half8*)&smem[ar * PAD + ac] = hv;
        *(half8*)&smem[2560 + br * PAD + bc] = w0;  *(half8*)&smem[2560 + br * PAD + bc + 8] = w1;
        *(half8*)&smem[7680 + br * PAD + bc] = w2;  *(half8*)&smem[7680 + br * PAD + bc + 8] = w3;
    }
    __syncthreads();

    int p = 0;
    for (int k0 = 0; k0 < HDIM; k0 += BK) {
        const int po = p * 12800;
        const bool nx = (k0 + BK) < HDIM;
        if (nx) {
            const float* xp = x + (size_t)(m0 + ar) * HDIM + k0 + BK + ac;
            xf0 = *(const float4*)xp;
            xf1 = *(const float4*)(xp + 4);
            const _Float16* bp1 = BreH + (size_t)(n0 + br) * HDIM + k0 + BK + bc;
            const _Float16* bp2 = BimH + (size_t)(n0 + br) * HDIM + k0 + BK + bc;
            w0 = *(const half8*)bp1;  w1 = *(const half8*)(bp1 + 8);
            w2 = *(const half8*)bp2;  w3 = *(const half8*)(bp2 + 8);
        }
        half8 af[2], bRf[4], bIf[4];
#pragma unroll
        for (int sm = 0; sm < 2; ++sm)
            af[sm] = *(const half8*)&smem[po + (wr * 32 + sm * 16 + fRC) * PAD + fKg];
#pragma unroll
        for (int sn = 0; sn < 4; ++sn) {
            bRf[sn] = *(const half8*)&smem[po + 2560 + (wc * 64 + sn * 16 + fRC) * PAD + fKg];
            bIf[sn] = *(const half8*)&smem[po + 7680 + (wc * 64 + sn * 16 + fRC) * PAD + fKg];
        }
#pragma unroll
        for (int sm = 0; sm < 2; ++sm)
#pragma unroll
            for (int sn = 0; sn < 4; ++sn) {
                accR[sm * 4 + sn] = __builtin_amdgcn_mfma_f32_16x16x32_f16(af[sm], bRf[sn], accR[sm * 4 + sn], 0, 0, 0);
                accI[sm * 4 + sn] = __builtin_amdgcn_mfma_f32_16x16x32_f16(af[sm], bIf[sn], accI[sm * 4 + sn], 0, 0, 0);
            }
        if (nx) {
            const int qo = (p ^ 1) * 12800;
            half8 hv;
            hv[0]=(_Float16)xf0.x; hv[1]=(_Float16)xf0.y; hv[2]=(_Float16)xf0.z; hv[3]=(_Float16)xf0.w;
            hv[4]=(_Float16)xf1.x; hv[5]=(_Float16)xf1.y; hv[6]=(_Float16)xf1.z; hv[7]=(_Float16)xf1.w;
            *(half8*)&smem[qo + ar * PAD + ac] = hv;
            *(half8*)&smem[qo + 2560 + br * PAD + bc] = w0;  *(half8*)&smem[qo + 2560 + br * PAD + bc + 8] = w1;
            *(half8*)&smem[qo + 7680 + br * PAD + bc] = w2;  *(half8*)&smem[qo + 7680 + br * PAD + bc + 8] = w3;
        }
        __syncthreads();
        p ^= 1;
    }
    // loop-final __syncthreads guarantees all fragment reads drained -> smem reusable

    _Float16* SRe = smem;          // [col][row], stride SSTR
    _Float16* SIm = smem + 8704;

    // Phase A: accumulators -> scan LDS (transposed), fp16
    const int rBase = (lane >> 4) * 4;
#pragma unroll
    for (int sm = 0; sm < 2; ++sm)
#pragma unroll
        for (int sn = 0; sn < 4; ++sn) {
            int col = wc * 64 + sn * 16 + fRC;
            int row = wr * 32 + sm * 16 + rBase;
            half4 h1, h2;
#pragma unroll
            for (int reg = 0; reg < 4; ++reg) {
                h1[reg] = (_Float16)accR[sm * 4 + sn][reg];
                h2[reg] = (_Float16)accI[sm * 4 + sn][reg];
            }
            *(half4*)&SRe[col * SSTR + row] = h1;
            *(half4*)&SIm[col * SSTR + row] = h2;
        }
    __syncthreads();

    // Phase B: per-column scan over 64 rows (fp32 state), threads 0..127
    if (tid < BN) {
        int col = tid;
        int n = n0 + col;
        float lr = lamRe[n], li = lamIm[n];
        _Float16* cR = &SRe[col * SSTR];
        _Float16* cI = &SIm[col * SSTR];
        float sr = 0.0f, si = 0.0f;
#pragma unroll 8
        for (int r = 0; r < CH; ++r) {
            float ur = (float)cR[r];
            float ui = (float)cI[r];
            float nr = fmaf(lr, sr, fmaf(-li, si, ur));
            float ni = fmaf(lr, si, fmaf(li, sr, ui));
            sr = nr; si = ni;
            cR[r] = (_Float16)sr;
            cI[r] = (_Float16)si;
        }
        int bb = blockIdx.x >> 6, cc = blockIdx.x & 63;
        size_t f = ((size_t)(bb * NC + cc)) * NDIM + n;
        finRe[f] = sr;
        finIm[f] = si;
    }
    __syncthreads();

    // Phase C: coalesced write of locally-scanned states to global (fp16)
    {
        int row = tid >> 2;
        int cb  = (tid & 3) * 32;
        size_t gbase = (size_t)(m0 + row) * NDIM + n0 + cb;
#pragma unroll
        for (int g = 0; g < 4; ++g) {
            half8 h1, h2;
#pragma unroll
            for (int e = 0; e < 8; ++e) {
                int col = cb + g * 8 + e;
                h1[e] = SRe[col * SSTR + row];
                h2[e] = SIm[col * SSTR + row];
            }
            *(half8*)(stReH + gbase + g * 8) = h1;
            *(half8*)(stImH + gbase + g * 8) = h2;
        }
    }
}

// ---------------------------------------------------------------------------
// k_carry: sequential prefix over chunk finals -> carry per chunk (fp32).
// Unrolled so the (independent) fin loads prefetch ahead of the FMA chain.
// ---------------------------------------------------------------------------
__launch_bounds__(256)
__global__ void k_carry(const float* __restrict__ lamRe,
                        const float* __restrict__ lamIm,
                        const float* __restrict__ finRe,
                        const float* __restrict__ finIm,
                        float* __restrict__ carRe,
                        float* __restrict__ carIm) {
    const int b = blockIdx.x;
    const int n = threadIdx.x;
    const float lr = lamRe[n];
    const float li = lamIm[n];
    float kr = 1.0f, ki = 0.0f;
#pragma unroll
    for (int i = 0; i < CH; ++i) {
        float t = kr * lr - ki * li;
        ki = fmaf(kr, li, ki * lr);
        kr = t;
    }
    float cr = 0.0f, ci = 0.0f;
#pragma unroll 8
    for (int c = 0; c < NC; ++c) {
        size_t idx = ((size_t)b * NC + c) * NDIM + n;
        carRe[idx] = cr;
        carIm[idx] = ci;
        float fr = finRe[idx];
        float fi = finIm[idx];
        float t = fmaf(kr, cr, fmaf(-ki, ci, fr));
        ci = fmaf(kr, ci, fmaf(ki, cr, fi));
        cr = t;
    }
}

// ---------------------------------------------------------------------------
// k_out: y = s @ CreH^T + sIm @ CimNH^T + x*D, with the chunk carry applied
// during A-staging: state[i] = local[i] + P[i]*carry  (P = Lambda^(i+1)).
// m-tile == one chunk (64 rows), so row index == local i, chunk = m0>>6.
// ---------------------------------------------------------------------------
__launch_bounds__(256)
__global__ void k_out(const _Float16* __restrict__ sReH,
                      const _Float16* __restrict__ sImH,
                      const _Float16* __restrict__ CreH,
                      const _Float16* __restrict__ CimNH,
                      const float* __restrict__ powRe,
                      const float* __restrict__ powIm,
                      const float* __restrict__ carRe,
                      const float* __restrict__ carIm,
                      const float* __restrict__ x,
                      const float* __restrict__ Dv,
                      float* __restrict__ y) {
    __shared__ __align__(16) _Float16 A1[2][BM * PAD];
    __shared__ __align__(16) _Float16 A2[2][BM * PAD];
    __shared__ __align__(16) _Float16 Cr[2][BN * PAD];
    __shared__ __align__(16) _Float16 Ci[2][BN * PAD];

    const int tid  = threadIdx.x;
    const int lane = tid & 63;
    const int wave = tid >> 6;
    const int wr   = wave >> 1;
    const int wc   = wave & 1;
    const int m0   = blockIdx.x * BM;
    const int h0   = blockIdx.y * BN;
    const int chunk = m0 >> 6;

    const int ar = tid >> 2, ac = (tid & 3) * 8;
    const int br = tid >> 1, bc = (tid & 1) * 16;

    const int fRC = lane & 15;
    const int fKg = (lane >> 4) * 8;

    fx4 acc[8];
#pragma unroll
    for (int i = 0; i < 8; ++i) acc[i] = (fx4)0.0f;

    half8 s1, s2, c0a, c0b, c1a, c1b;
    float4 pr0, pr1, pi0, pi1, cr0, cr1, ci0, ci1;

#define LOAD_STAGE(K0)                                                          \
    {                                                                           \
        size_t aOff = (size_t)(m0 + ar) * NDIM + (K0) + ac;                     \
        s1 = *(const half8*)(sReH + aOff);                                      \
        s2 = *(const half8*)(sImH + aOff);                                      \
        size_t pOff = (size_t)ar * NDIM + (K0) + ac;                            \
        pr0 = *(const float4*)(powRe + pOff); pr1 = *(const float4*)(powRe + pOff + 4); \
        pi0 = *(const float4*)(powIm + pOff); pi1 = *(const float4*)(powIm + pOff + 4); \
        size_t cOff = (size_t)chunk * NDIM + (K0) + ac;                         \
        cr0 = *(const float4*)(carRe + cOff); cr1 = *(const float4*)(carRe + cOff + 4); \
        ci0 = *(const float4*)(carIm + cOff); ci1 = *(const float4*)(carIm + cOff + 4); \
        const _Float16* cp1 = CreH  + (size_t)(h0 + br) * NDIM + (K0) + bc;     \
        const _Float16* cp2 = CimNH + (size_t)(h0 + br) * NDIM + (K0) + bc;     \
        c0a = *(const half8*)cp1;  c0b = *(const half8*)(cp1 + 8);              \
        c1a = *(const half8*)cp2;  c1b = *(const half8*)(cp2 + 8);              \
    }

#define WRITE_STAGE(P)                                                          \
    {                                                                           \
        float prA[8] = {pr0.x,pr0.y,pr0.z,pr0.w,pr1.x,pr1.y,pr1.z,pr1.w};       \
        float piA[8] = {pi0.x,pi0.y,pi0.z,pi0.w,pi1.x,pi1.y,pi1.z,pi1.w};       \
        float crA[8] = {cr0.x,cr0.y,cr0.z,cr0.w,cr1.x,cr1.y,cr1.z,cr1.w};       \
        float ciA[8] = {ci0.x,ci0.y,ci0.z,ci0.w,ci1.x,ci1.y,ci1.z,ci1.w};       \
        half8 h1, h2;                                                           \
        _Pragma("unroll")                                                       \
        for (int e = 0; e < 8; ++e) {                                           \
            float ur = fmaf(prA[e], crA[e], fmaf(-piA[e], ciA[e], (float)s1[e])); \
            float ui = fmaf(prA[e], ciA[e], fmaf( piA[e], crA[e], (float)s2[e])); \
            h1[e] = (_Float16)ur; h2[e] = (_Float16)ui;                         \
        }                                                                       \
        *(half8*)&A1[P][ar * PAD + ac] = h1;                                    \
        *(half8*)&A2[P][ar * PAD + ac] = h2;                                    \
        *(half8*)&Cr[P][br * PAD + bc] = c0a;  *(half8*)&Cr[P][br * PAD + bc + 8] = c0b; \
        *(half8*)&Ci[P][br * PAD + bc] = c1a;  *(half8*)&Ci[P][br * PAD + bc + 8] = c1b; \
    }

    LOAD_STAGE(0);
    WRITE_STAGE(0);
    __syncthreads();

    int p = 0;
    for (int k0 = 0; k0 < NDIM; k0 += BK) {
        const bool nx = (k0 + BK) < NDIM;
        if (nx) LOAD_STAGE(k0 + BK);
        half8 a1[2], a2[2], bRf[4], bIf[4];
#pragma unroll
        for (int sm = 0; sm < 2; ++sm) {
            a1[sm] = *(const half8*)&A1[p][(wr * 32 + sm * 16 + fRC) * PAD + fKg];
            a2[sm] = *(const half8*)&A2[p][(wr * 32 + sm * 16 + fRC) * PAD + fKg];
        }
#pragma unroll
        for (int sn = 0; sn < 4; ++sn) {
            bRf[sn] = *(const half8*)&Cr[p][(wc * 64 + sn * 16 + fRC) * PAD + fKg];
            bIf[sn] = *(const half8*)&Ci[p][(wc * 64 + sn * 16 + fRC) * PAD + fKg];
        }
#pragma unroll
        for (int sm = 0; sm < 2; ++sm)
#pragma unroll
            for (int sn = 0; sn < 4; ++sn) {
                acc[sm * 4 + sn] = __builtin_amdgcn_mfma_f32_16x16x32_f16(a1[sm], bRf[sn], acc[sm * 4 + sn], 0, 0, 0);
                acc[sm * 4 + sn] = __builtin_amdgcn_mfma_f32_16x16x32_f16(a2[sm], bIf[sn], acc[sm * 4 + sn], 0, 0, 0);
            }
        if (nx) WRITE_STAGE(p ^ 1);
        __syncthreads();
        p ^= 1;
    }

    float d[4];
#pragma unroll
    for (int sn = 0; sn < 4; ++sn) d[sn] = Dv[h0 + wc * 64 + sn * 16 + fRC];

    const int rBase = (lane >> 4) * 4;
#pragma unroll
    for (int sm = 0; sm < 2; ++sm)
#pragma unroll
        for (int sn = 0; sn < 4; ++sn) {
            int h = h0 + wc * 64 + sn * 16 + fRC;
#pragma unroll
            for (int reg = 0; reg < 4; ++reg) {
                int m = m0 + wr * 32 + sm * 16 + rBase + reg;
                size_t idx = (size_t)m * HDIM + h;
                y[idx] = fmaf(x[idx], d[sn], acc[sm * 4 + sn][reg]);
            }
        }
#undef LOAD_STAGE
#undef WRITE_STAGE
}

// ---------------------------------------------------------------------------
extern "C" void kernel_launch(void* const* d_in, const int* in_sizes, int n_in,
                              void* d_out, int out_size, void* d_ws, size_t ws_size,
                              hipStream_t stream) {
    const float* x      = (const float*)d_in[0];
    const float* B_re   = (const float*)d_in[1];
    const float* B_im   = (const float*)d_in[2];
    const float* C_re   = (const float*)d_in[3];
    const float* C_im   = (const float*)d_in[4];
    const float* nu_log = (const float*)d_in[5];
    const float* th_log = (const float*)d_in[6];
    const float* D      = (const float*)d_in[7];
    float* y = (float*)d_out;

    char* p = (char*)d_ws;
    _Float16* stReH = (_Float16*)p;  p += (size_t)MROWS * NDIM * 2;
    _Float16* stImH = (_Float16*)p;  p += (size_t)MROWS * NDIM * 2;
    _Float16* BreH  = (_Float16*)p;  p += (size_t)NDIM * HDIM * 2;
    _Float16* BimH  = (_Float16*)p;  p += (size_t)NDIM * HDIM * 2;
    _Float16* CreH  = (_Float16*)p;  p += (size_t)HDIM * NDIM * 2;
    _Float16* CimNH = (_Float16*)p;  p += (size_t)HDIM * NDIM * 2;
    float* lamRe = (float*)p;  p += NDIM * 4;
    float* lamIm = (float*)p;  p += NDIM * 4;
    float* powRe = (float*)p;  p += (size_t)CH * NDIM * 4;
    float* powIm = (float*)p;  p += (size_t)CH * NDIM * 4;
    float* finRe = (float*)p;  p += (size_t)B_SZ * NC * NDIM * 4;
    float* finIm = (float*)p;  p += (size_t)B_SZ * NC * NDIM * 4;
    float* carRe = (float*)p;  p += (size_t)B_SZ * NC * NDIM * 4;
    float* carIm = (float*)p;  p += (size_t)B_SZ * NC * NDIM * 4;

    k_prep<<<NDIM, 256, 0, stream>>>(B_re, B_im, C_re, C_im, nu_log, th_log,
                                     BreH, BimH, CreH, CimNH, lamRe, lamIm,
                                     powRe, powIm);

    dim3 gGemm(MROWS / BM, NDIM / BN);
    k_buscan<<<gGemm, 256, 0, stream>>>(x, BreH, BimH, lamRe, lamIm,
                                        stReH, stImH, finRe, finIm);

    k_carry<<<B_SZ, 256, 0, stream>>>(lamRe, lamIm, finRe, finIm, carRe, carIm);

    dim3 gOut(MROWS / BM, HDIM / BN);
    k_out<<<gOut, 256, 0, stream>>>(stReH, stImH, CreH, CimNH,
                                    powRe, powIm, carRe, carIm, x, D, y);
}